// Round 1
// baseline (6309.937 us; speedup 1.0000x reference)
//
#include <hip/hip_runtime.h>
#include <stdint.h>

// ---------------------------------------------------------------------------
// GRU embedder: B=128, T=256, D=128, H=512, L=3, reset_after=True, then
// Hrep = sigmoid(out @ Wd + bd).
//
// Strategy: persistent scan kernel per layer. 32 scan workgroups =
// 8 batch-tiles (M=16) x 4 hidden-chunks (Hc=128). Each of 8 waves in a wg
// owns one 16-wide j-tile => z/r/h fragments for the same (batch,j) are in
// the same lane; fp32 hidden state lives in VGPRs for all 256 steps.
// Weights pre-packed bf16 in MFMA fragment order. Cross-wg h exchange via
// device-coherent stores/loads + relaxed agent-scope monotonic flags.
// Layer 2 fuses dense+sigmoid via 8 extra wgs reading a 16-slot ring.
// ---------------------------------------------------------------------------

typedef short vs8 __attribute__((ext_vector_type(8)));   // 8 x bf16
typedef float vf4 __attribute__((ext_vector_type(4)));
typedef int   vi4 __attribute__((ext_vector_type(4)));

#define DEVFN __device__ __forceinline__

constexpr int BB = 128, TT = 256, HH = 512, DD = 128;

// ws layout (bytes)
constexpr size_t OFF_FLAGS = 0;                       // 512 B (3*32 flags + 8 dprog)
constexpr size_t OFF_BIAS  = 512;                     // 3*4*512*4 = 24576
constexpr size_t OFF_WDP   = 25088;                   // 32*16*64*16 = 524288
constexpr size_t OFF_WP0   = 549376;                  // 96*20*1024 = 1966080
constexpr size_t OFF_WP1   = 2515456;                 // 96*32*1024 = 3145728
constexpr size_t OFF_WP2   = 5661184;                 // 3145728
constexpr size_t OFF_YB    = 8806912;                 // 256*128*512*2 = 33554432
constexpr size_t OFF_RING  = 42361344;                // 16*128*512*2 = 2097152
// total 44458496 bytes (~42.4 MB) of d_ws

DEVFN ushort f2bf(float f) {
  union { float f; uint u; } x; x.f = f;
  uint r = (x.u + 0x7FFFu + ((x.u >> 16) & 1u)) >> 16;
  return (ushort)r;
}

DEVFN vf4 mfma16(vs8 a, vs8 b, vf4 c) {
  return __builtin_amdgcn_mfma_f32_16x16x32_bf16(a, b, c, 0, 0, 0);
}

// device-coherent 16B loads (bypass non-coherent caches; pair + single wait)
DEVFN void ld16x2_coh(const ushort* p0, const ushort* p1, vi4& a, vi4& b) {
  asm volatile("global_load_dwordx4 %0, %2, off sc0 sc1\n\t"
               "global_load_dwordx4 %1, %3, off sc0 sc1\n\t"
               "s_waitcnt vmcnt(0)"
               : "=&v"(a), "=&v"(b) : "v"(p0), "v"(p1) : "memory");
}
// device-coherent 2B store
DEVFN void st2_coh(ushort* p, ushort v) {
  uint vv = v;
  asm volatile("global_store_short %0, %1, off sc0 sc1" :: "v"(p), "v"(vv) : "memory");
}

DEVFN void poll4(uint* f, uint need) {
  int lane = threadIdx.x & 63;
  for (;;) {
    uint v = need;
    if (lane < 4) v = __hip_atomic_load(&f[lane], __ATOMIC_RELAXED, __HIP_MEMORY_SCOPE_AGENT);
    if (__all((int)(v >= need))) break;
    __builtin_amdgcn_s_sleep(2);
  }
}
DEVFN void poll1(uint* f, uint need) {
  int lane = threadIdx.x & 63;
  for (;;) {
    uint v = need;
    if (lane == 0) v = __hip_atomic_load(f, __ATOMIC_RELAXED, __HIP_MEMORY_SCOPE_AGENT);
    if (__all((int)(v >= need))) break;
    __builtin_amdgcn_s_sleep(2);
  }
}

// ---------------------------------------------------------------------------
// prep kernels
// ---------------------------------------------------------------------------

// pack weights to bf16 MFMA-fragment order: block (tile,ks) -> 64 lanes x 8:
// elem(lane,i) = W[k = ks*32 + (lane>>4)*8 + i][col = tile*16 + (lane&15)]
// tiles: z = 0..31, r = 32..63, h = 64..95 (cols 0..1535 natural order).
__global__ void pack_weights(
    const float* __restrict__ k0,    // [128][1536]
    const float* __restrict__ krest, // [2][512][1536]
    const float* __restrict__ rec,   // [3][512][1536]
    const float* __restrict__ wd,    // [512][512]
    ushort* __restrict__ wp0, ushort* __restrict__ wp1, ushort* __restrict__ wp2,
    ushort* __restrict__ wdp) {
  const int bid = blockIdx.x, lane = threadIdx.x;
  if (bid >= 8064) {                          // Wd: 32 tiles x 16 ksteps
    int rel = bid - 8064;
    int tile = rel >> 4, ks = rel & 15;
    int col = tile * 16 + (lane & 15);
    int kb = ks * 32 + (lane >> 4) * 8;
    vs8 o;
#pragma unroll
    for (int i = 0; i < 8; ++i) o[i] = (short)f2bf(wd[(size_t)(kb + i) * 512 + col]);
    *(vs8*)&wdp[((size_t)rel * 64 + lane) * 8] = o;
    return;
  }
  const float* WK; const float* UU; ushort* dst; int KS, DinL, rel;
  if (bid < 1920)      { rel = bid;        WK = k0;                          UU = rec;                           dst = wp0; KS = 20; DinL = 128; }
  else if (bid < 4992) { rel = bid - 1920; WK = krest;                       UU = rec + (size_t)512 * 1536;      dst = wp1; KS = 32; DinL = 512; }
  else                 { rel = bid - 4992; WK = krest + (size_t)512 * 1536;  UU = rec + (size_t)2 * 512 * 1536;  dst = wp2; KS = 32; DinL = 512; }
  int tile = rel / KS, ks = rel % KS;
  int col = tile * 16 + (lane & 15);
  int kb = ks * 32 + (lane >> 4) * 8;
  vs8 o;
#pragma unroll
  for (int i = 0; i < 8; ++i) {
    int k = kb + i;
    float v = (k < DinL) ? WK[(size_t)k * 1536 + col] : UU[(size_t)(k - DinL) * 1536 + col];
    o[i] = (short)f2bf(v);
  }
  *(vs8*)&dst[((size_t)rel * 64 + lane) * 8] = o;
}

// X [B][T][128] fp32 -> XBF [T][B][128] bf16
__global__ void pack_x(const float* __restrict__ X, ushort* __restrict__ XBF) {
  int id = blockIdx.x * 256 + threadIdx.x;    // 524288 = T*B*16
  int oct = id & 15, bt = id >> 4;
  int b = bt & 127, t = bt >> 7;
  const float* src = X + ((size_t)b * TT + t) * DD + oct * 8;
  vs8 o;
#pragma unroll
  for (int i = 0; i < 8; ++i) o[i] = (short)f2bf(src[i]);
  *(vs8*)&XBF[(size_t)id * 8] = o;
}

// bias combine: [l][4][512] = { b_in_z+b_rec_z, b_in_r+b_rec_r, b_in_h, b_rec_h }
__global__ void pack_bias(const float* __restrict__ bsrc, float* __restrict__ bp) {
  int l = blockIdx.x, j = threadIdx.x;
  const float* a = bsrc + (size_t)l * 2 * 1536;
  const float* b = a + 1536;
  bp[l * 2048 + j]        = a[j] + b[j];
  bp[l * 2048 + 512 + j]  = a[512 + j] + b[512 + j];
  bp[l * 2048 + 1024 + j] = a[1024 + j];
  bp[l * 2048 + 1536 + j] = b[1024 + j];
}

// ---------------------------------------------------------------------------
// persistent scan kernel (one per layer); LAST also runs 8 dense wgs
// ---------------------------------------------------------------------------
template<int DIN, bool RING, bool LAST>
__global__ __launch_bounds__(512) void gru_scan(
    const ushort* __restrict__ Wp,    // packed [96][KS][64][8]
    const float*  __restrict__ biasL, // [4][512]
    const ushort* __restrict__ Xin,   // [T][B][DIN] bf16 (prev layer / XBF)
    ushort* __restrict__ Yout,        // [T][B][512] or ring [16][B][512]
    uint* __restrict__ flags,         // [32] this layer (monotonic step counts)
    uint* __restrict__ dprog,         // [8]  dense progress (LAST)
    const ushort* __restrict__ WdP,   // [32][16][64][8] (LAST)
    const float*  __restrict__ bdv,   // [512] (LAST)
    float* __restrict__ dOut)         // [B][T][512] fp32 (LAST)
{
  constexpr int KX = DIN / 32;
  constexpr int KS = KX + 16;
  __shared__ __align__(16) ushort ldsX[DIN * 16];   // [DIN/8][16][8]
  __shared__ __align__(16) ushort ldsH[512 * 16];   // [64][16][8]
  const int bid = blockIdx.x;
  const int tid = threadIdx.x;
  const int lane = tid & 63;
  const int wv = tid >> 6;
  const int rs = lane >> 4;

  if (!LAST || bid < 32) {
    // ---- scan role: wg(m,c); same-c wgs share weight chunk on one XCD ----
    const int xcd = bid & 7, idx = bid >> 3;
    const int c = xcd & 3, m = (xcd >> 2) * 4 + idx;
    const int b0 = m * 16;
    const int jt = c * 8 + wv;                  // j-tile [0,32)
    const int j  = jt * 16 + (lane & 15);       // hidden index
    const float bzc = biasL[j], brc = biasL[512 + j];
    const float bih = biasL[1024 + j], brh = biasL[1536 + j];
    const ushort* WpZ = Wp + (size_t)jt * KS * 512;
    const ushort* WpR = Wp + (size_t)(32 + jt) * KS * 512;
    const ushort* WpH = Wp + (size_t)(64 + jt) * KS * 512;
    float hst[4] = {0.f, 0.f, 0.f, 0.f};        // fp32 h-state, (b0+rs*4+i, j)
    uint* gf = flags + m * 4;

    for (int t = 0; t < TT; ++t) {
      if (t > 0) poll4(gf, (uint)t);                       // peers' h(t-1) ready
      if (LAST && t >= 16) poll1(&dprog[m], (uint)(t - 15)); // ring backpressure
      // stage x panel (cross-kernel data: plain cached loads)
      {
        const ushort* xs = Xin + ((size_t)t * BB + b0) * DIN;
        for (int cid = tid; cid < DIN * 2; cid += 512) {
          int row = cid & 15, koct = cid >> 4;
          vi4 v = *(const vi4*)(xs + (size_t)row * DIN + koct * 8);
          *(vi4*)&ldsX[(size_t)cid * 8] = v;
        }
      }
      // stage h panel (same-kernel cross-wg data: coherent loads)
      if (t > 0) {
        const ushort* hs;
        if (RING) hs = Yout + (size_t)((t - 1) & 15) * BB * 512 + (size_t)b0 * 512;
        else      hs = Yout + ((size_t)(t - 1) * BB + b0) * 512;
        int row = tid & 15, koct = tid >> 4;
        const ushort* p0 = hs + (size_t)row * 512 + koct * 8;
        vi4 a, b;
        ld16x2_coh(p0, p0 + 256, a, b);
        *(vi4*)&ldsH[(size_t)tid * 8] = a;
        *(vi4*)&ldsH[(size_t)(tid + 512) * 8] = b;
      }
      __syncthreads();
      vf4 aZ = {0,0,0,0}, aR = {0,0,0,0}, aXH = {0,0,0,0}, aHH = {0,0,0,0};
#pragma unroll
      for (int ks = 0; ks < KX; ++ks) {
        vs8 a  = *(const vs8*)&ldsX[((size_t)((ks * 4 + rs) * 16 + (lane & 15))) * 8];
        vs8 bz = *(const vs8*)&WpZ[((size_t)ks * 64 + lane) * 8];
        vs8 br = *(const vs8*)&WpR[((size_t)ks * 64 + lane) * 8];
        vs8 bh = *(const vs8*)&WpH[((size_t)ks * 64 + lane) * 8];
        aZ = mfma16(a, bz, aZ); aR = mfma16(a, br, aR); aXH = mfma16(a, bh, aXH);
      }
      if (t > 0) {
#pragma unroll
        for (int ks = 0; ks < 16; ++ks) {
          vs8 a  = *(const vs8*)&ldsH[((size_t)((ks * 4 + rs) * 16 + (lane & 15))) * 8];
          const int gk = KX + ks;
          vs8 bz = *(const vs8*)&WpZ[((size_t)gk * 64 + lane) * 8];
          vs8 br = *(const vs8*)&WpR[((size_t)gk * 64 + lane) * 8];
          vs8 bh = *(const vs8*)&WpH[((size_t)gk * 64 + lane) * 8];
          aZ = mfma16(a, bz, aZ); aR = mfma16(a, br, aR); aHH = mfma16(a, bh, aHH);
        }
      }
      ushort* yd = RING ? (Yout + (size_t)(t & 15) * BB * 512)
                        : (Yout + (size_t)t * BB * 512);
#pragma unroll
      for (int i = 0; i < 4; ++i) {
        float z = 1.f / (1.f + __expf(-(aZ[i] + bzc)));
        float r = 1.f / (1.f + __expf(-(aR[i] + brc)));
        float pre = aXH[i] + bih + r * (aHH[i] + brh);
        float e = __expf(-2.f * fabsf(pre));
        float th = (1.f - e) / (1.f + e);
        th = (pre < 0.f) ? -th : th;
        float hn = z * hst[i] + (1.f - z) * th;
        hst[i] = hn;
        int b = b0 + rs * 4 + i;
        st2_coh(yd + (size_t)b * 512 + j, f2bf(hn));
      }
      // drain inline-asm coherent stores (invisible to compiler's counter)
      asm volatile("s_waitcnt vmcnt(0)" ::: "memory");
      __syncthreads();
      if (tid == 0)
        __hip_atomic_store(&gf[c], (uint)(t + 1), __ATOMIC_RELAXED, __HIP_MEMORY_SCOPE_AGENT);
    }
  } else {
    // ---- dense role (LAST): out = sigmoid(h_t @ Wd + bd) ----
    const int m = bid - 32;
    const int b0 = m * 16;
    float bdq[4];
#pragma unroll
    for (int q = 0; q < 4; ++q) bdq[q] = bdv[(wv * 4 + q) * 16 + (lane & 15)];
    for (int t = 0; t < TT; ++t) {
      poll4(flags + m * 4, (uint)(t + 1));
      {
        const ushort* hs = Yout + (size_t)(t & 15) * BB * 512 + (size_t)b0 * 512;
        int row = tid & 15, koct = tid >> 4;
        const ushort* p0 = hs + (size_t)row * 512 + koct * 8;
        vi4 a, b;
        ld16x2_coh(p0, p0 + 256, a, b);
        *(vi4*)&ldsH[(size_t)tid * 8] = a;
        *(vi4*)&ldsH[(size_t)(tid + 512) * 8] = b;
      }
      __syncthreads();
      if (tid == 0)   // ring slot consumed -> release producers
        __hip_atomic_store(&dprog[m], (uint)(t + 1), __ATOMIC_RELAXED, __HIP_MEMORY_SCOPE_AGENT);
      vf4 acc[4] = {{0,0,0,0},{0,0,0,0},{0,0,0,0},{0,0,0,0}};
#pragma unroll
      for (int ks = 0; ks < 16; ++ks) {
        vs8 a = *(const vs8*)&ldsH[((size_t)((ks * 4 + rs) * 16 + (lane & 15))) * 8];
#pragma unroll
        for (int q = 0; q < 4; ++q) {
          vs8 b = *(const vs8*)&WdP[((size_t)((wv * 4 + q) * 16 + ks) * 64 + lane) * 8];
          acc[q] = mfma16(a, b, acc[q]);
        }
      }
#pragma unroll
      for (int q = 0; q < 4; ++q) {
        int jd = (wv * 4 + q) * 16 + (lane & 15);
#pragma unroll
        for (int i = 0; i < 4; ++i) {
          float v = acc[q][i] + bdq[q];
          float s = 1.f / (1.f + __expf(-v));
          int b = b0 + rs * 4 + i;
          dOut[((size_t)b * TT + t) * 512 + jd] = s;
        }
      }
      __syncthreads();
    }
  }
}

// ---------------------------------------------------------------------------
extern "C" void kernel_launch(void* const* d_in, const int* in_sizes, int n_in,
                              void* d_out, int out_size, void* d_ws, size_t ws_size,
                              hipStream_t stream) {
  (void)in_sizes; (void)n_in; (void)out_size; (void)ws_size;
  const float* X     = (const float*)d_in[0];
  const float* k0    = (const float*)d_in[1];
  const float* krest = (const float*)d_in[2];
  const float* rec   = (const float*)d_in[3];
  const float* bsrc  = (const float*)d_in[4];
  const float* wd    = (const float*)d_in[5];
  const float* bd    = (const float*)d_in[6];

  uint8_t* ws = (uint8_t*)d_ws;
  uint*   flags = (uint*)(ws + OFF_FLAGS);     // [96] layer flags + [8] dprog
  float*  bp    = (float*)(ws + OFF_BIAS);
  ushort* wdp   = (ushort*)(ws + OFF_WDP);
  ushort* wp0   = (ushort*)(ws + OFF_WP0);
  ushort* wp1   = (ushort*)(ws + OFF_WP1);
  ushort* wp2   = (ushort*)(ws + OFF_WP2);
  ushort* YB    = (ushort*)(ws + OFF_YB);
  ushort* RINGB = (ushort*)(ws + OFF_RING);
  // XBF and layer-0 output live inside d_out (fully consumed before the
  // fused dense kernel overwrites d_out with fp32 results).
  ushort* XBF = (ushort*)d_out;                              // 8 MB
  ushort* YA  = (ushort*)((uint8_t*)d_out + 8388608);        // 32 MB
  float*  out = (float*)d_out;

  hipMemsetAsync(flags, 0, 512, stream);
  pack_weights<<<8576, 64, 0, stream>>>(k0, krest, rec, wd, wp0, wp1, wp2, wdp);
  pack_bias<<<3, 512, 0, stream>>>(bsrc, bp);
  pack_x<<<2048, 256, 0, stream>>>(X, XBF);

  gru_scan<128, false, false><<<32, 512, 0, stream>>>(wp0, bp,        XBF, YA,    flags,      nullptr,    nullptr, nullptr, nullptr);
  gru_scan<512, false, false><<<32, 512, 0, stream>>>(wp1, bp + 2048, YA,  YB,    flags + 32, nullptr,    nullptr, nullptr, nullptr);
  gru_scan<512, true,  true ><<<40, 512, 0, stream>>>(wp2, bp + 4096, YB,  RINGB, flags + 64, flags + 96, wdp,     bd,      out);
}

// Round 4
// 5411.330 us; speedup vs baseline: 1.1661x; 1.1661x over previous
//
#include <hip/hip_runtime.h>
#include <stdint.h>

// ---------------------------------------------------------------------------
// GRU embedder: B=128, T=256, D=128, H=512, L=3, reset_after, then
// Hrep = sigmoid(out @ Wd + bd).
//
// Round-1 proven skeleton (3 sequential persistent scan kernels, device-scope
// sc0sc1 h-exchange + relaxed agent-scope monotonic flags, dense fused into
// the last kernel via ring + backpressure), weights held in VGPRs.
//
// Round-3 bug fixed here: h-ready flags are now per (mh, jc, mp) — 128 per
// layer — so the two batch-halves never alias the same flag slot. Dense role
// polls the correct (mh, mp) quadrant: mhd = dp>>2, mpd = (dp>>1)&1.
// Ring shrunk 16 -> 8 slots to keep ws under the proven footprint.
// ---------------------------------------------------------------------------

typedef short vs8 __attribute__((ext_vector_type(8)));   // 8 x bf16 (4 VGPRs)
typedef float vf4 __attribute__((ext_vector_type(4)));

#define DEVFN __device__ __forceinline__

constexpr int TT = 256, BB = 128;

// ws layout (bytes)
constexpr size_t OFF_FLAGS = 0;         // fh[3][128] + dprog[16] = 1600 B (pad 2048)
constexpr size_t OFF_BIAS  = 2048;      // [3][4][512] f32 = 24576
constexpr size_t OFF_WDP   = 26624;     // [32][16][64][8] bf16 = 524288
constexpr size_t OFF_WP0   = 550912;    // [96][20][64][8] = 1966080
constexpr size_t OFF_WP1   = 2516992;   // [96][32][64][8] = 3145728
constexpr size_t OFF_WP2   = 5662720;   // 3145728
constexpr size_t OFF_RING  = 8808448;   // [8][128][512] bf16 = 1048576
constexpr size_t OFF_H1    = 9857024;   // [256][128][512] bf16 = 33554432
// end 43411456 (< round-1 proven 44458496)

DEVFN ushort f2bf(float f) {
  union { float f; uint u; } x; x.f = f;
  uint r = (x.u + 0x7FFFu + ((x.u >> 16) & 1u)) >> 16;
  return (ushort)r;
}
DEVFN vf4 mfma16(vs8 a, vs8 b, vf4 c) {
  return __builtin_amdgcn_mfma_f32_16x16x32_bf16(a, b, c, 0, 0, 0);
}

// device-coherent 2B store (round-1 proven)
DEVFN void st2_coh(ushort* p, ushort v) {
  uint vv = v;
  asm volatile("global_store_short %0, %1, off sc0 sc1" :: "v"(p), "v"(vv) : "memory");
}

// ---- polls: relaxed agent-scope monotonic flags (round-1 proven) ----------
DEVFN void poll32s2(const uint* f, int mp, uint need, int lane) {
  const uint* q = f + (((lane & 31) << 1) | mp);
  for (;;) {
    uint v = __hip_atomic_load(q, __ATOMIC_RELAXED, __HIP_MEMORY_SCOPE_AGENT);
    if (__all((int)(v >= need))) break;
    __builtin_amdgcn_s_sleep(1);
  }
  asm volatile("" ::: "memory");
}
DEVFN void poll4(const uint* f, uint need, int lane) {
  for (;;) {
    uint v = need;
    if (lane < 4) v = __hip_atomic_load(f + lane, __ATOMIC_RELAXED, __HIP_MEMORY_SCOPE_AGENT);
    if (__all((int)(v >= need))) break;
    __builtin_amdgcn_s_sleep(1);
  }
  asm volatile("" ::: "memory");
}

// issue NKS pairs of coherent 16B A-frag loads, one wait, fence the scheduler
template<int NKS>
DEVFN void load_frags_coh(const ushort* base, int row0, int lane,
                          vs8 (&f0)[NKS], vs8 (&f1)[NKS]) {
  const ushort* p0 = base + (size_t)(row0 + (lane & 15)) * 512 + ((lane >> 4) << 3);
  const ushort* p1 = p0 + 16 * 512;
#pragma unroll
  for (int ks = 0; ks < NKS; ++ks) {
    asm volatile("global_load_dwordx4 %0, %1, off sc0 sc1" : "=v"(f0[ks]) : "v"(p0 + ks * 32));
    asm volatile("global_load_dwordx4 %0, %1, off sc0 sc1" : "=v"(f1[ks]) : "v"(p1 + ks * 32));
  }
  asm volatile("s_waitcnt vmcnt(0)" ::: "memory");
  __builtin_amdgcn_sched_barrier(0);
}

// ---------------------------------------------------------------------------
// prep kernels (identical to round-1 proven versions)
// ---------------------------------------------------------------------------
__global__ void pack_weights(
    const float* __restrict__ k0, const float* __restrict__ krest,
    const float* __restrict__ rec, const float* __restrict__ wd,
    ushort* __restrict__ wp0, ushort* __restrict__ wp1, ushort* __restrict__ wp2,
    ushort* __restrict__ wdp) {
  const int bid = blockIdx.x, lane = threadIdx.x;
  if (bid >= 8064) {                         // Wd: 32 tiles x 16 ksteps
    int rel = bid - 8064;
    int tile = rel >> 4, ks = rel & 15;
    int col = tile * 16 + (lane & 15);
    int kb = ks * 32 + (lane >> 4) * 8;
    vs8 o;
#pragma unroll
    for (int i = 0; i < 8; ++i) o[i] = (short)f2bf(wd[(size_t)(kb + i) * 512 + col]);
    *(vs8*)&wdp[((size_t)rel * 64 + lane) * 8] = o;
    return;
  }
  const float* WK; const float* UU; ushort* dst; int KS, DinL, rel;
  if (bid < 1920)      { rel = bid;        WK = k0;                         UU = rec;                          dst = wp0; KS = 20; DinL = 128; }
  else if (bid < 4992) { rel = bid - 1920; WK = krest;                      UU = rec + (size_t)512 * 1536;     dst = wp1; KS = 32; DinL = 512; }
  else                 { rel = bid - 4992; WK = krest + (size_t)512 * 1536; UU = rec + (size_t)2 * 512 * 1536; dst = wp2; KS = 32; DinL = 512; }
  int tile = rel / KS, ks = rel % KS;
  int col = tile * 16 + (lane & 15);
  int kb = ks * 32 + (lane >> 4) * 8;
  vs8 o;
#pragma unroll
  for (int i = 0; i < 8; ++i) {
    int k = kb + i;
    float v = (k < DinL) ? WK[(size_t)k * 1536 + col] : UU[(size_t)(k - DinL) * 1536 + col];
    o[i] = (short)f2bf(v);
  }
  *(vs8*)&dst[((size_t)rel * 64 + lane) * 8] = o;
}

__global__ void pack_x(const float* __restrict__ X, ushort* __restrict__ XBF) {
  int id = blockIdx.x * 256 + threadIdx.x;   // T*B*16
  int oct = id & 15, bt = id >> 4;
  int b = bt & 127, t = bt >> 7;
  const float* src = X + ((size_t)b * TT + t) * 128 + oct * 8;
  vs8 o;
#pragma unroll
  for (int i = 0; i < 8; ++i) o[i] = (short)f2bf(src[i]);
  *(vs8*)&XBF[(size_t)id * 8] = o;
}

__global__ void pack_bias(const float* __restrict__ bsrc, float* __restrict__ bp) {
  int l = blockIdx.x, j = threadIdx.x;
  const float* a = bsrc + (size_t)l * 2 * 1536;
  const float* b = a + 1536;
  bp[l * 2048 + j]        = a[j] + b[j];
  bp[l * 2048 + 512 + j]  = a[512 + j] + b[512 + j];
  bp[l * 2048 + 1024 + j] = a[1024 + j];
  bp[l * 2048 + 1536 + j] = b[1024 + j];
}

// ---------------------------------------------------------------------------
// persistent scan kernel (weights in VGPRs); LAST fuses dense via 8-slot ring
// ---------------------------------------------------------------------------
template<int KX, bool LAST>
__global__ __launch_bounds__(256, 1) void gru_scan(
    const ushort* __restrict__ Wp,    // packed [96][KS][64][8]
    const float*  __restrict__ biasL, // [4][512]
    const ushort* __restrict__ Xin,   // [T][B][DIN] bf16
    ushort* __restrict__ Hbuf,        // [T][B][512] or ring [8][B][512]
    uint* __restrict__ fh,            // [128] this layer: [mh][jc][mp]
    uint* __restrict__ dprog,         // [16] (LAST)
    const ushort* __restrict__ WdP,   // [32][16][64][8] (LAST)
    const float*  __restrict__ bdv,   // [512] (LAST)
    float* __restrict__ dOut)         // [B][T][512] fp32 (LAST)
{
  constexpr int DIN = KX * 32;
  constexpr int KS = KX + 16;
  __shared__ __align__(16) float pacc[2 * 2 * 64 * 24];   // [slot][mp][lane][6*vf4]
  const int bid = blockIdx.x;
  const int tid = threadIdx.x;
  const int lane = tid & 63;
  const int wv = tid >> 6;
  const int rs = lane >> 4;

  if (LAST && bid >= 64) {
    // ---- dense role: out_t = sigmoid(h_t @ Wd + bd), 16 rows x 256 cols ----
    const int dp = (bid - 64) >> 1, jh = (bid - 64) & 1;
    const int mhd = dp >> 2;                 // which batch-half these rows are
    const int mpd = (dp >> 1) & 1;           // which row-pair quadrant
    float bq[4];
#pragma unroll
    for (int u = 0; u < 4; ++u) bq[u] = bdv[(jh * 16 + wv * 4 + u) * 16 + (lane & 15)];
    for (int t = 0; t < TT; ++t) {
      poll32s2(fh + mhd * 64, mpd, (uint)(t + 1), lane);
      const ushort* base = Hbuf + (size_t)(t & 7) * BB * 512
                         + (size_t)(dp * 16 + (lane & 15)) * 512 + ((lane >> 4) << 3);
      vs8 fr[16];
#pragma unroll
      for (int ks = 0; ks < 16; ++ks)
        asm volatile("global_load_dwordx4 %0, %1, off sc0 sc1" : "=v"(fr[ks]) : "v"(base + ks * 32));
      asm volatile("s_waitcnt vmcnt(0)" ::: "memory");
      __builtin_amdgcn_sched_barrier(0);
      __syncthreads();                 // all 4 waves have consumed slot t
      if (tid == 0)
        __hip_atomic_store(&dprog[bid - 64], (uint)(t + 1), __ATOMIC_RELAXED, __HIP_MEMORY_SCOPE_AGENT);
      vf4 acc[4] = {{0,0,0,0},{0,0,0,0},{0,0,0,0},{0,0,0,0}};
#pragma unroll
      for (int ks = 0; ks < 16; ++ks)
#pragma unroll
        for (int u = 0; u < 4; ++u) {
          vs8 b = *(const vs8*)&WdP[(((size_t)(jh * 16 + wv * 4 + u) * 16 + ks) * 64 + lane) * 8];
          acc[u] = mfma16(fr[ks], b, acc[u]);
        }
#pragma unroll
      for (int u = 0; u < 4; ++u) {
        int col = (jh * 16 + wv * 4 + u) * 16 + (lane & 15);
#pragma unroll
        for (int i = 0; i < 4; ++i) {
          float v = acc[u][i] + bq[u];
          float s = 1.f / (1.f + __expf(-v));
          int b = dp * 16 + rs * 4 + i;
          dOut[((size_t)b * TT + t) * 512 + col] = s;
        }
      }
      __syncthreads();
    }
    return;
  }

  // ---- scan role ----
  const int mh = bid >> 5, jc = bid & 31;
  const int mp = wv & 1;
  const bool xw = (wv < 2);
  const int rowA = mh * 64 + mp * 32;
  const int ks0 = xw ? 0 : KX;
  const int NK = xw ? KX : 16;
  uint* fhq = fh + mh * 64;                  // this half's flag quadrant base

  // weight slice -> VGPRs, once
  vs8 w[3][16];
#pragma unroll
  for (int g = 0; g < 3; ++g)
#pragma unroll
    for (int k = 0; k < 16; ++k)
      if (k < NK)
        w[g][k] = *(const vs8*)(Wp + (((size_t)(g * 32 + jc) * KS + ks0 + k) * 64 + lane) * 8);

  const int j = jc * 16 + (lane & 15);
  float bzc = 0.f, brc = 0.f, bih = 0.f, brh = 0.f;
  if (!xw) { bzc = biasL[j]; brc = biasL[512 + j]; bih = biasL[1024 + j]; brh = biasL[1536 + j]; }
  float hst[2][4] = {{0, 0, 0, 0}, {0, 0, 0, 0}};
  const int p0x2 = (mh * 4 + mp * 2) * 2;    // dprog base for this wave's rows

  for (int t = 0; t < TT; ++t) {
    if (xw) {
      // x-projection for step t: plain loads (input immutable), no polls
      const ushort* xb = Xin + (size_t)t * BB * DIN;
      const ushort* q0 = xb + (size_t)(rowA + (lane & 15)) * DIN + ((lane >> 4) << 3);
      const ushort* q1 = q0 + (size_t)16 * DIN;
      vf4 ax[2][3] = {};
#pragma unroll
      for (int ks = 0; ks < KX; ++ks) {
        vs8 a0 = *(const vs8*)(q0 + ks * 32);
        vs8 a1 = *(const vs8*)(q1 + ks * 32);
#pragma unroll
        for (int g = 0; g < 3; ++g) {
          ax[0][g] = mfma16(a0, w[g][ks], ax[0][g]);
          ax[1][g] = mfma16(a1, w[g][ks], ax[1][g]);
        }
      }
      float* pd = &pacc[(((size_t)(t & 1) * 2 + mp) * 64 + lane) * 24];
#pragma unroll
      for (int m = 0; m < 2; ++m)
#pragma unroll
        for (int g = 0; g < 3; ++g)
          *(vf4*)&pd[(m * 3 + g) * 4] = ax[m][g];
      __syncthreads();
      // nothing after the barrier for x-waves
    } else {
      vf4 ah[2][3] = {};
      if (t > 0) {
        poll32s2(fhq, mp, (uint)t, lane);    // own half's peers published h(t-1)
        const ushort* hsrc = LAST ? (Hbuf + (size_t)((t - 1) & 7) * BB * 512)
                                  : (Hbuf + (size_t)(t - 1) * BB * 512);
        vs8 f0[16], f1[16];
        load_frags_coh<16>(hsrc, rowA, lane, f0, f1);
#pragma unroll
        for (int ks = 0; ks < 16; ++ks)
#pragma unroll
          for (int g = 0; g < 3; ++g) {
            ah[0][g] = mfma16(f0[ks], w[g][ks], ah[0][g]);
            ah[1][g] = mfma16(f1[ks], w[g][ks], ah[1][g]);
          }
      }
      __syncthreads();
      // combine with x partials, gate math
      const float* ps = &pacc[(((size_t)(t & 1) * 2 + mp) * 64 + lane) * 24];
      ushort hv[2][4];
#pragma unroll
      for (int m = 0; m < 2; ++m) {
        vf4 pz = *(const vf4*)&ps[(m * 3 + 0) * 4];
        vf4 pr = *(const vf4*)&ps[(m * 3 + 1) * 4];
        vf4 ph = *(const vf4*)&ps[(m * 3 + 2) * 4];
#pragma unroll
        for (int i = 0; i < 4; ++i) {
          float z = 1.f / (1.f + __expf(-(pz[i] + ah[m][0][i] + bzc)));
          float r = 1.f / (1.f + __expf(-(pr[i] + ah[m][1][i] + brc)));
          float pre = ph[i] + bih + r * (ah[m][2][i] + brh);
          float e = __expf(-2.f * fabsf(pre));
          float th = (1.f - e) / (1.f + e);
          th = (pre < 0.f) ? -th : th;
          float hn = z * hst[m][i] + (1.f - z) * th;
          hst[m][i] = hn;
          hv[m][i] = f2bf(hn);
        }
      }
      if (LAST && t >= 8) poll4(dprog + p0x2, (uint)(t - 7), lane);  // ring backpressure
      ushort* hd = LAST ? (Hbuf + (size_t)(t & 7) * BB * 512)
                        : (Hbuf + (size_t)t * BB * 512);
#pragma unroll
      for (int m = 0; m < 2; ++m)
#pragma unroll
        for (int i = 0; i < 4; ++i) {
          int row = rowA + m * 16 + rs * 4 + i;
          st2_coh(hd + (size_t)row * 512 + j, hv[m][i]);
        }
      asm volatile("s_waitcnt vmcnt(0)" ::: "memory");
      if (lane == 0)
        __hip_atomic_store(&fhq[jc * 2 + mp], (uint)(t + 1), __ATOMIC_RELAXED, __HIP_MEMORY_SCOPE_AGENT);
    }
  }
}

// ---------------------------------------------------------------------------
extern "C" void kernel_launch(void* const* d_in, const int* in_sizes, int n_in,
                              void* d_out, int out_size, void* d_ws, size_t ws_size,
                              hipStream_t stream) {
  (void)in_sizes; (void)n_in; (void)out_size; (void)ws_size;
  const float* X     = (const float*)d_in[0];
  const float* k0    = (const float*)d_in[1];
  const float* krest = (const float*)d_in[2];
  const float* rec   = (const float*)d_in[3];
  const float* bsrc  = (const float*)d_in[4];
  const float* wd    = (const float*)d_in[5];
  const float* bd    = (const float*)d_in[6];
  uint8_t* ws = (uint8_t*)d_ws;

  uint*   flags = (uint*)(ws + OFF_FLAGS);   // fh[3][128], dprog[16]
  float*  bp    = (float*)(ws + OFF_BIAS);
  ushort* wdp   = (ushort*)(ws + OFF_WDP);
  ushort* wp0   = (ushort*)(ws + OFF_WP0);
  ushort* wp1   = (ushort*)(ws + OFF_WP1);
  ushort* wp2   = (ushort*)(ws + OFF_WP2);
  ushort* ring  = (ushort*)(ws + OFF_RING);
  ushort* H1    = (ushort*)(ws + OFF_H1);
  // XBF (8MB) + H0 (32MB) live in d_out; both fully consumed before the
  // fused dense kernel overwrites d_out with the fp32 result (67MB).
  ushort* XBF = (ushort*)d_out;
  ushort* H0  = (ushort*)((uint8_t*)d_out + 8388608);
  float*  out = (float*)d_out;

  hipMemsetAsync(flags, 0, 2048, stream);
  pack_weights<<<8576, 64, 0, stream>>>(k0, krest, rec, wd, wp0, wp1, wp2, wdp);
  pack_bias<<<3, 512, 0, stream>>>(bsrc, bp);
  pack_x<<<2048, 256, 0, stream>>>(X, XBF);

  gru_scan<4,  false><<<64, 256, 0, stream>>>(wp0, bp,        XBF, H0,   flags,       nullptr,     nullptr, nullptr, nullptr);
  gru_scan<16, false><<<64, 256, 0, stream>>>(wp1, bp + 2048, H0,  H1,   flags + 128, nullptr,     nullptr, nullptr, nullptr);
  gru_scan<16, true ><<<80, 256, 0, stream>>>(wp2, bp + 4096, H1,  ring, flags + 256, flags + 384, wdp,     bd,      out);
}

// Round 5
// 2304.871 us; speedup vs baseline: 2.7377x; 2.3478x over previous
//
#include <hip/hip_runtime.h>
#include <stdint.h>

// ---------------------------------------------------------------------------
// GRU embedder: B=128, T=256, D=128, H=512, L=3, reset_after, then
// Hrep = sigmoid(out @ Wd + bd).
//
// Single fused persistent kernel: 192 scan wgs (3 layers x 2 batch-halves x
// 32 col-chunks) + 16 dense wgs = 208 wgs <= 256 CUs (co-resident by
// capacity). Weights in VGPRs (round-4 proven). Inter-layer hand-off via
// 16-slot rings + consumer-progress backpressure (scan->dense ring proven in
// round 4; replicated for scan->scan). All data coherent sc0sc1; all flags
// relaxed agent-scope monotonic counters with UNIQUE writers (round-3 lesson).
// h publication coalesced: gate fragments transposed through same-wave LDS,
// one 16B store per lane instead of eight 2B stores.
// ---------------------------------------------------------------------------

typedef short vs8 __attribute__((ext_vector_type(8)));   // 8 x bf16 (4 VGPRs)
typedef float vf4 __attribute__((ext_vector_type(4)));

#define DEVFN __device__ __forceinline__

constexpr int TT = 256, BB = 128;

// ws layout (bytes). Flag area (uint indices): fh0@0 fh1@128 fh2@256 (each
// [mh][jc][mp]=64*2), dprog@384 [16], xprogA@512 [128], xprogB@640 [128].
constexpr size_t OFF_FLAGS = 0;         // 4096 B
constexpr size_t OFF_BIAS  = 4096;      // [3][4][512] f32 = 24576
constexpr size_t OFF_WDP   = 28672;     // [32][16][64][8] bf16 = 524288
constexpr size_t OFF_WP0   = 552960;    // [96][20][64][8] = 1966080
constexpr size_t OFF_WP1   = 2519040;   // [96][32][64][8] = 3145728
constexpr size_t OFF_WP2   = 5664768;   // 3145728
constexpr size_t OFF_XBF   = 8810496;   // [256][128][128] bf16 = 8388608
constexpr size_t OFF_R0    = 17199104;  // [16][128][512] bf16 = 2097152
constexpr size_t OFF_R1    = 19296256;  // 2097152
constexpr size_t OFF_R2    = 21393408;  // 2097152
// end 23490560 (~22.4 MB), well under the round-1-proven 44.4 MB footprint

DEVFN ushort f2bf(float f) {
  union { float f; uint u; } x; x.f = f;
  uint r = (x.u + 0x7FFFu + ((x.u >> 16) & 1u)) >> 16;
  return (ushort)r;
}
DEVFN vf4 mfma16(vs8 a, vs8 b, vf4 c) {
  return __builtin_amdgcn_mfma_f32_16x16x32_bf16(a, b, c, 0, 0, 0);
}

// device-coherent 16B store
DEVFN void stg16_coh(ushort* p, vs8 v) {
  asm volatile("global_store_dwordx4 %0, %1, off sc0 sc1" :: "v"(p), "v"(v) : "memory");
}

// ---- relaxed agent-scope monotonic flags (rounds 1/4 proven) --------------
DEVFN void stflag(uint* p, uint v) {
  __hip_atomic_store(p, v, __ATOMIC_RELAXED, __HIP_MEMORY_SCOPE_AGENT);
}
DEVFN void poll32s2(const uint* f, int mp, uint need, int lane) {
  const uint* q = f + (((lane & 31) << 1) | mp);
  for (;;) {
    uint v = __hip_atomic_load(q, __ATOMIC_RELAXED, __HIP_MEMORY_SCOPE_AGENT);
    if (__all((int)(v >= need))) break;
    __builtin_amdgcn_s_sleep(1);
  }
  asm volatile("" ::: "memory");
}
DEVFN void poll4(const uint* f, uint need, int lane) {
  for (;;) {
    uint v = need;
    if (lane < 4) v = __hip_atomic_load(f + lane, __ATOMIC_RELAXED, __HIP_MEMORY_SCOPE_AGENT);
    if (__all((int)(v >= need))) break;
    __builtin_amdgcn_s_sleep(1);
  }
  asm volatile("" ::: "memory");
}

// issue 2*NKS coherent 16B A-frag loads, one wait, fence the scheduler
template<int NKS>
DEVFN void load_frags_coh(const ushort* base, int row0, int lane,
                          vs8 (&f0)[NKS], vs8 (&f1)[NKS]) {
  const ushort* p0 = base + (size_t)(row0 + (lane & 15)) * 512 + ((lane >> 4) << 3);
  const ushort* p1 = p0 + 16 * 512;
#pragma unroll
  for (int ks = 0; ks < NKS; ++ks) {
    asm volatile("global_load_dwordx4 %0, %1, off sc0 sc1" : "=v"(f0[ks]) : "v"(p0 + ks * 32));
    asm volatile("global_load_dwordx4 %0, %1, off sc0 sc1" : "=v"(f1[ks]) : "v"(p1 + ks * 32));
  }
  asm volatile("s_waitcnt vmcnt(0)" ::: "memory");
  __builtin_amdgcn_sched_barrier(0);
}

// ---------------------------------------------------------------------------
// prep kernels (identical to proven versions)
// ---------------------------------------------------------------------------
__global__ void pack_weights(
    const float* __restrict__ k0, const float* __restrict__ krest,
    const float* __restrict__ rec, const float* __restrict__ wd,
    ushort* __restrict__ wp0, ushort* __restrict__ wp1, ushort* __restrict__ wp2,
    ushort* __restrict__ wdp) {
  const int bid = blockIdx.x, lane = threadIdx.x;
  if (bid >= 8064) {                         // Wd: 32 tiles x 16 ksteps
    int rel = bid - 8064;
    int tile = rel >> 4, ks = rel & 15;
    int col = tile * 16 + (lane & 15);
    int kb = ks * 32 + (lane >> 4) * 8;
    vs8 o;
#pragma unroll
    for (int i = 0; i < 8; ++i) o[i] = (short)f2bf(wd[(size_t)(kb + i) * 512 + col]);
    *(vs8*)&wdp[((size_t)rel * 64 + lane) * 8] = o;
    return;
  }
  const float* WK; const float* UU; ushort* dst; int KS, DinL, rel;
  if (bid < 1920)      { rel = bid;        WK = k0;                         UU = rec;                          dst = wp0; KS = 20; DinL = 128; }
  else if (bid < 4992) { rel = bid - 1920; WK = krest;                      UU = rec + (size_t)512 * 1536;     dst = wp1; KS = 32; DinL = 512; }
  else                 { rel = bid - 4992; WK = krest + (size_t)512 * 1536; UU = rec + (size_t)2 * 512 * 1536; dst = wp2; KS = 32; DinL = 512; }
  int tile = rel / KS, ks = rel % KS;
  int col = tile * 16 + (lane & 15);
  int kb = ks * 32 + (lane >> 4) * 8;
  vs8 o;
#pragma unroll
  for (int i = 0; i < 8; ++i) {
    int k = kb + i;
    float v = (k < DinL) ? WK[(size_t)k * 1536 + col] : UU[(size_t)(k - DinL) * 1536 + col];
    o[i] = (short)f2bf(v);
  }
  *(vs8*)&dst[((size_t)rel * 64 + lane) * 8] = o;
}

__global__ void pack_x(const float* __restrict__ X, ushort* __restrict__ XBF) {
  int id = blockIdx.x * 256 + threadIdx.x;   // T*B*16
  int oct = id & 15, bt = id >> 4;
  int b = bt & 127, t = bt >> 7;
  const float* src = X + ((size_t)b * TT + t) * 128 + oct * 8;
  vs8 o;
#pragma unroll
  for (int i = 0; i < 8; ++i) o[i] = (short)f2bf(src[i]);
  *(vs8*)&XBF[(size_t)id * 8] = o;
}

__global__ void pack_bias(const float* __restrict__ bsrc, float* __restrict__ bp) {
  int l = blockIdx.x, j = threadIdx.x;
  const float* a = bsrc + (size_t)l * 2 * 1536;
  const float* b = a + 1536;
  bp[l * 2048 + j]        = a[j] + b[j];
  bp[l * 2048 + 512 + j]  = a[512 + j] + b[512 + j];
  bp[l * 2048 + 1024 + j] = a[1024 + j];
  bp[l * 2048 + 1536 + j] = b[1024 + j];
}

// ---------------------------------------------------------------------------
// scan body: one (layer, mh, jc) wg. wv0,1 = x-waves, wv2,3 = h-waves.
// ---------------------------------------------------------------------------
template<int KX, bool FIRST, bool LASTL>
DEVFN void scan_body(const ushort* __restrict__ Wp, const float* __restrict__ biasL,
                     const ushort* __restrict__ Xsrc, ushort* __restrict__ ring,
                     uint* fh_self, const uint* fh_prev,
                     uint* xprog_self, const uint* bpf,
                     int mh, int jc, int tid,
                     float* pacc, ushort* hT) {
  const int lane = tid & 63;
  const int wv = tid >> 6;
  const int rs = lane >> 4;
  const int mp = wv & 1;
  const bool xw = (wv < 2);
  const int rowA = mh * 64 + mp * 32;
  constexpr int KS = KX + 16;
  const int ks0 = xw ? 0 : KX;
  const int NK = xw ? KX : 16;

  // weight slice -> VGPRs, once
  vs8 w[3][16];
#pragma unroll
  for (int g = 0; g < 3; ++g)
#pragma unroll
    for (int k = 0; k < 16; ++k)
      if (k < NK)
        w[g][k] = *(const vs8*)(Wp + (((size_t)(g * 32 + jc) * KS + ks0 + k) * 64 + lane) * 8);

  const int j = jc * 16 + (lane & 15);
  float bzc = 0.f, brc = 0.f, bih = 0.f, brh = 0.f;
  if (!xw) { bzc = biasL[j]; brc = biasL[512 + j]; bih = biasL[1024 + j]; brh = biasL[1536 + j]; }
  float hst[2][4] = {{0, 0, 0, 0}, {0, 0, 0, 0}};

  for (int t = 0; t < TT; ++t) {
    if (xw) {
      // ---- x-projection wave: x(t) @ Wk -> pacc ----
      vf4 ax[2][3] = {};
      if (FIRST) {
        const ushort* xb = Xsrc + (size_t)t * BB * 128;
        const ushort* q0 = xb + (size_t)(rowA + (lane & 15)) * 128 + ((lane >> 4) << 3);
        const ushort* q1 = q0 + (size_t)16 * 128;
#pragma unroll
        for (int ks = 0; ks < KX; ++ks) {
          vs8 a0 = *(const vs8*)(q0 + ks * 32);
          vs8 a1 = *(const vs8*)(q1 + ks * 32);
#pragma unroll
          for (int g = 0; g < 3; ++g) {
            ax[0][g] = mfma16(a0, w[g][ks], ax[0][g]);
            ax[1][g] = mfma16(a1, w[g][ks], ax[1][g]);
          }
        }
      } else {
        // wait for prev layer's h(t) rows of this (mh, mp) block
        poll32s2(fh_prev + mh * 64, mp, (uint)(t + 1), lane);
        const ushort* xb = Xsrc + (size_t)(t & 15) * BB * 512;
        vs8 f0[16], f1[16];
        load_frags_coh<16>(xb, rowA, lane, f0, f1);
        if (lane == 0) stflag(&xprog_self[mh * 64 + jc * 2 + mp], (uint)(t + 1));
#pragma unroll
        for (int ks = 0; ks < 16; ++ks)
#pragma unroll
          for (int g = 0; g < 3; ++g) {
            ax[0][g] = mfma16(f0[ks], w[g][ks], ax[0][g]);
            ax[1][g] = mfma16(f1[ks], w[g][ks], ax[1][g]);
          }
      }
      float* pd = &pacc[(((size_t)(t & 1) * 2 + mp) * 64 + lane) * 24];
#pragma unroll
      for (int m = 0; m < 2; ++m)
#pragma unroll
        for (int g = 0; g < 3; ++g)
          *(vf4*)&pd[(m * 3 + g) * 4] = ax[m][g];
      __syncthreads();
    } else {
      // ---- recurrence wave: h(t-1) @ U -> gates -> publish h(t) ----
      vf4 ah[2][3] = {};
      if (t > 0) {
        poll32s2(fh_self + mh * 64, mp, (uint)t, lane);   // peers' h(t-1) ready
        const ushort* hsrc = ring + (size_t)((t - 1) & 15) * BB * 512;
        vs8 f0[16], f1[16];
        load_frags_coh<16>(hsrc, rowA, lane, f0, f1);
#pragma unroll
        for (int ks = 0; ks < 16; ++ks)
#pragma unroll
          for (int g = 0; g < 3; ++g) {
            ah[0][g] = mfma16(f0[ks], w[g][ks], ah[0][g]);
            ah[1][g] = mfma16(f1[ks], w[g][ks], ah[1][g]);
          }
      }
      __syncthreads();
      // combine with x partials, gate math
      const float* ps = &pacc[(((size_t)(t & 1) * 2 + mp) * 64 + lane) * 24];
#pragma unroll
      for (int m = 0; m < 2; ++m) {
        vf4 pz = *(const vf4*)&ps[(m * 3 + 0) * 4];
        vf4 pr = *(const vf4*)&ps[(m * 3 + 1) * 4];
        vf4 ph = *(const vf4*)&ps[(m * 3 + 2) * 4];
#pragma unroll
        for (int i = 0; i < 4; ++i) {
          float z = 1.f / (1.f + __expf(-(pz[i] + ah[m][0][i] + bzc)));
          float r = 1.f / (1.f + __expf(-(pr[i] + ah[m][1][i] + brc)));
          float pre = ph[i] + bih + r * (ah[m][2][i] + brh);
          float e = __expf(-2.f * fabsf(pre));
          float th = (1.f - e) / (1.f + e);
          th = (pre < 0.f) ? -th : th;
          float hn = z * hst[m][i] + (1.f - z) * th;
          hst[m][i] = hn;
          // same-wave LDS transpose buffer (no cross-wave deps)
          hT[(size_t)(mp * 32 + m * 16 + rs * 4 + i) * 16 + (lane & 15)] = f2bf(hn);
        }
      }
      // backpressure before overwriting ring slot t&15 (held step t-16)
      if (t >= 16) {
        if (LASTL) poll4(bpf + (mh * 4 + mp * 2) * 2, (uint)(t - 15), lane);
        else       poll32s2(bpf + mh * 64, mp, (uint)(t - 15), lane);
      }
      // coalesced publish: one 16B sc0sc1 store per lane
      const int flat = mp * 64 + lane;          // 0..127 over the two h-waves
      const int hr = flat >> 1, ch = flat & 1;  // hr in own wave's 32-row block
      ushort* dst = ring + (size_t)(t & 15) * BB * 512
                  + (size_t)(mh * 64 + hr) * 512 + jc * 16 + ch * 8;
      vs8 v = *(const vs8*)&hT[(size_t)hr * 16 + ch * 8];
      stg16_coh(dst, v);
      asm volatile("s_waitcnt vmcnt(0)" ::: "memory");
      if (lane == 0) stflag(&fh_self[mh * 64 + jc * 2 + mp], (uint)(t + 1));
    }
  }
}

// ---------------------------------------------------------------------------
// dense body (round-4 proven, ring widened to 16 slots)
// ---------------------------------------------------------------------------
DEVFN void dense_body(const ushort* __restrict__ ring2, const uint* fh2,
                      uint* dprog, const ushort* __restrict__ WdP,
                      const float* __restrict__ bdv, float* __restrict__ dOut,
                      int rel, int tid) {
  const int lane = tid & 63, wv = tid >> 6, rs = lane >> 4;
  const int dp = rel >> 1, jh = rel & 1;
  const int mhd = dp >> 2;
  const int mpd = (dp >> 1) & 1;
  float bq[4];
#pragma unroll
  for (int u = 0; u < 4; ++u) bq[u] = bdv[(jh * 16 + wv * 4 + u) * 16 + (lane & 15)];
  for (int t = 0; t < TT; ++t) {
    poll32s2(fh2 + mhd * 64, mpd, (uint)(t + 1), lane);
    const ushort* base = ring2 + (size_t)(t & 15) * BB * 512
                       + (size_t)(dp * 16 + (lane & 15)) * 512 + ((lane >> 4) << 3);
    vs8 fr[16];
#pragma unroll
    for (int ks = 0; ks < 16; ++ks)
      asm volatile("global_load_dwordx4 %0, %1, off sc0 sc1" : "=v"(fr[ks]) : "v"(base + ks * 32));
    asm volatile("s_waitcnt vmcnt(0)" ::: "memory");
    __builtin_amdgcn_sched_barrier(0);
    __syncthreads();                   // all 4 waves consumed slot t
    if (tid == 0) stflag(&dprog[rel], (uint)(t + 1));
    vf4 acc[4] = {{0,0,0,0},{0,0,0,0},{0,0,0,0},{0,0,0,0}};
#pragma unroll
    for (int ks = 0; ks < 16; ++ks)
#pragma unroll
      for (int u = 0; u < 4; ++u) {
        vs8 b = *(const vs8*)&WdP[(((size_t)(jh * 16 + wv * 4 + u) * 16 + ks) * 64 + lane) * 8];
        acc[u] = mfma16(fr[ks], b, acc[u]);
      }
#pragma unroll
    for (int u = 0; u < 4; ++u) {
      int col = (jh * 16 + wv * 4 + u) * 16 + (lane & 15);
#pragma unroll
      for (int i = 0; i < 4; ++i) {
        float v = acc[u][i] + bq[u];
        float s = 1.f / (1.f + __expf(-v));
        int b = dp * 16 + rs * 4 + i;
        dOut[((size_t)b * TT + t) * 512 + col] = s;
      }
    }
    __syncthreads();
  }
}

// ---------------------------------------------------------------------------
// fused persistent kernel: 192 scan wgs + 16 dense wgs
// ---------------------------------------------------------------------------
__global__ __launch_bounds__(256, 1) void gru_fused(uint8_t* __restrict__ ws,
                                                    const float* __restrict__ bd,
                                                    float* __restrict__ dOut) {
  __shared__ __align__(16) float pacc[2 * 2 * 64 * 24];   // 24 KB
  __shared__ __align__(16) ushort hT[64 * 16];            // 2 KB
  const int bid = blockIdx.x;
  const int tid = threadIdx.x;

  uint* flags = (uint*)(ws + OFF_FLAGS);
  uint* fh0 = flags, *fh1 = flags + 128, *fh2 = flags + 256;
  uint* dprog = flags + 384;
  uint* xprogA = flags + 512, *xprogB = flags + 640;
  const float* bp = (const float*)(ws + OFF_BIAS);
  const ushort* wdp = (const ushort*)(ws + OFF_WDP);
  const ushort* wp0 = (const ushort*)(ws + OFF_WP0);
  const ushort* wp1 = (const ushort*)(ws + OFF_WP1);
  const ushort* wp2 = (const ushort*)(ws + OFF_WP2);
  const ushort* xbf = (const ushort*)(ws + OFF_XBF);
  ushort* r0 = (ushort*)(ws + OFF_R0);
  ushort* r1 = (ushort*)(ws + OFF_R1);
  ushort* r2 = (ushort*)(ws + OFF_R2);

  if (bid < 192) {
    const int l = bid >> 6, rem = bid & 63;
    const int mh = rem >> 5, jc = rem & 31;
    if (l == 0)
      scan_body<4, true, false>(wp0, bp, xbf, r0, fh0, nullptr, nullptr, xprogA,
                                mh, jc, tid, pacc, hT);
    else if (l == 1)
      scan_body<16, false, false>(wp1, bp + 2048, r0, r1, fh1, fh0, xprogA, xprogB,
                                  mh, jc, tid, pacc, hT);
    else
      scan_body<16, false, true>(wp2, bp + 4096, r1, r2, fh2, fh1, xprogB, dprog,
                                 mh, jc, tid, pacc, hT);
  } else {
    dense_body(r2, fh2, dprog, wdp, bd, dOut, bid - 192, tid);
  }
}

// ---------------------------------------------------------------------------
extern "C" void kernel_launch(void* const* d_in, const int* in_sizes, int n_in,
                              void* d_out, int out_size, void* d_ws, size_t ws_size,
                              hipStream_t stream) {
  (void)in_sizes; (void)n_in; (void)out_size; (void)ws_size;
  const float* X     = (const float*)d_in[0];
  const float* k0    = (const float*)d_in[1];
  const float* krest = (const float*)d_in[2];
  const float* rec   = (const float*)d_in[3];
  const float* bsrc  = (const float*)d_in[4];
  const float* wd    = (const float*)d_in[5];
  const float* bd    = (const float*)d_in[6];
  uint8_t* ws = (uint8_t*)d_ws;

  hipMemsetAsync(ws + OFF_FLAGS, 0, 4096, stream);
  pack_weights<<<8576, 64, 0, stream>>>(k0, krest, rec, wd,
      (ushort*)(ws + OFF_WP0), (ushort*)(ws + OFF_WP1), (ushort*)(ws + OFF_WP2),
      (ushort*)(ws + OFF_WDP));
  pack_bias<<<3, 512, 0, stream>>>(bsrc, (float*)(ws + OFF_BIAS));
  pack_x<<<2048, 256, 0, stream>>>(X, (ushort*)(ws + OFF_XBF));

  gru_fused<<<208, 256, 0, stream>>>(ws, bd, (float*)d_out);
}